// Round 1
// baseline (320.944 us; speedup 1.0000x reference)
//
#include <hip/hip_runtime.h>
#include <stdint.h>

// Problem constants
#define B_   2
#define T_   4096
#define C_   768
#define H_   12
#define D_   64
#define BH_  24      // B_*H_
#define M_   8192    // B_*T_
#define K_   768
#define N1_  2304    // 3*C_

typedef short bf16x8 __attribute__((ext_vector_type(8)));
typedef float f32x4  __attribute__((ext_vector_type(4)));

typedef const __attribute__((address_space(1))) void* as1cv;
typedef __attribute__((address_space(3))) void*       as3v;

__device__ __forceinline__ void gload_lds16(const void* g, void* l) {
  __builtin_amdgcn_global_load_lds((as1cv)g, (as3v)l, 16, 0, 0);
}

// fp32 -> bf16 bits, round-to-nearest-even (values are always finite here)
__device__ __forceinline__ unsigned short f2bf(float f) {
  uint32_t x = __builtin_bit_cast(uint32_t, f);
  uint32_t r = (x + 0x7fffu + ((x >> 16) & 1u)) >> 16;
  return (unsigned short)r;
}

__device__ __forceinline__ uint32_t pk2bf(float lo, float hi) {
  return ((uint32_t)f2bf(hi) << 16) | (uint32_t)f2bf(lo);
}

// ---------------------------------------------------------------- cast x -> bf16
__global__ void cast_kernel(const float* __restrict__ in, unsigned short* __restrict__ out, int n4) {
  int idx = blockIdx.x * blockDim.x + threadIdx.x;
  int stride = gridDim.x * blockDim.x;
  for (int i = idx; i < n4; i += stride) {
    float4 v = reinterpret_cast<const float4*>(in)[i];
    ushort4 o;
    o.x = f2bf(v.x); o.y = f2bf(v.y); o.z = f2bf(v.z); o.w = f2bf(v.w);
    reinterpret_cast<ushort4*>(out)[i] = o;
  }
}

// ------------------------------------------- transpose + cast: in[K][N] -> out[N][K] bf16
__global__ void transpose_cast(const float* __restrict__ in, unsigned short* __restrict__ out,
                               int K, int N) {
  __shared__ float tile[32][33];
  const int tx = threadIdx.x, ty = threadIdx.y;
  const int n = blockIdx.x * 32 + tx;
  #pragma unroll
  for (int r = 0; r < 4; ++r) {
    int k = blockIdx.y * 32 + ty + r * 8;
    tile[ty + r * 8][tx] = in[(size_t)k * N + n];
  }
  __syncthreads();
  const int k = blockIdx.y * 32 + tx;
  #pragma unroll
  for (int r = 0; r < 4; ++r) {
    int nn = blockIdx.x * 32 + ty + r * 8;
    out[(size_t)nn * K + k] = f2bf(tile[tx][ty + r * 8]);
  }
}

// ---------------------------------------------------------------- GEMM (m97-like)
// C[M][N] = A[M][768] * BT[N][768]^T + bias
// MODE 0: scatter epilogue -> Q (x0.125), K as [BH][T][D], V transposed to [BH][D][T], bf16
// MODE 1: plain fp32 store to fo[M][768]
template <int MODE>
__global__ __launch_bounds__(256) void gemm_kernel(
    const unsigned short* __restrict__ A, const unsigned short* __restrict__ BT,
    const float* __restrict__ bias,
    unsigned short* __restrict__ o0, unsigned short* __restrict__ o1,
    unsigned short* __restrict__ o2, float* __restrict__ fo) {
  __shared__ __align__(16) unsigned short Al[128 * 32];
  __shared__ __align__(16) unsigned short Bl[128 * 32];
  const int tid = threadIdx.x;
  const int w = tid >> 6, lane = tid & 63;
  const int g = lane >> 4, c16 = lane & 15;
  const int wr = w >> 1, wc = w & 1;
  const int m0 = blockIdx.x * 128, n0 = blockIdx.y * 128;

  f32x4 acc[4][4] = {};

  for (int k0 = 0; k0 < K_; k0 += 32) {
    __syncthreads();
    #pragma unroll
    for (int q = 0; q < 2; ++q) {
      const int ch = (w * 2 + q) * 64 + lane;     // 0..511
      const int row = ch >> 2, kb = ch & 3;       // 128 rows x 4 x 16B
      gload_lds16(A  + (size_t)(m0 + row) * K_ + k0 + kb * 8, &Al[(w * 2 + q) * 512]);
      gload_lds16(BT + (size_t)(n0 + row) * K_ + k0 + kb * 8, &Bl[(w * 2 + q) * 512]);
    }
    __syncthreads();
    bf16x8 af[4], bfr[4];
    #pragma unroll
    for (int i = 0; i < 4; ++i) {
      af[i]  = *reinterpret_cast<const bf16x8*>(&Al[(wr * 64 + i * 16 + c16) * 32 + g * 8]);
      bfr[i] = *reinterpret_cast<const bf16x8*>(&Bl[(wc * 64 + i * 16 + c16) * 32 + g * 8]);
    }
    #pragma unroll
    for (int i = 0; i < 4; ++i)
      #pragma unroll
      for (int j = 0; j < 4; ++j)
        acc[i][j] = __builtin_amdgcn_mfma_f32_16x16x32_bf16(af[i], bfr[j], acc[i][j], 0, 0, 0);
  }

  const int which = (MODE == 0) ? (n0 / 768) : 0;
  #pragma unroll
  for (int i = 0; i < 4; ++i) {
    const int mbase = m0 + wr * 64 + i * 16 + g * 4;
    #pragma unroll
    for (int j2 = 0; j2 < 4; ++j2) {
      const int n = n0 + wc * 64 + j2 * 16 + c16;
      const float bv = bias[n];
      #pragma unroll
      for (int j = 0; j < 4; ++j) {
        float v = acc[i][j2][j] + bv;
        const int mm = mbase + j;
        if constexpr (MODE == 0) {
          const int cc = n - which * 768;
          const int hh = cc >> 6, dd = cc & 63;
          const int bb = mm >> 12, tt = mm & 4095;
          const size_t bh = (size_t)bb * H_ + hh;
          if (which == 0)      o0[(bh * T_ + tt) * D_ + dd] = f2bf(v * 0.125f); // Q pre-scaled
          else if (which == 1) o1[(bh * T_ + tt) * D_ + dd] = f2bf(v);          // K
          else                 o2[(bh * D_ + dd) * T_ + tt] = f2bf(v);          // V^T
        } else {
          fo[(size_t)mm * 768 + n] = v;
        }
      }
    }
  }
}

// ---------------------------------------------------------------- flash attention
// Grid (64, 24): block handles 64 q-rows of one (b,h); 4 waves x 16 q-rows.
// K/V staged in LDS per 32-kv tile (XOR-swizzled via pre-swizzled global source).
__global__ __launch_bounds__(256) void attn_kernel(
    const unsigned short* __restrict__ Qb, const unsigned short* __restrict__ Kb,
    const unsigned short* __restrict__ Vt, unsigned short* __restrict__ Yb) {
  __shared__ __align__(16) unsigned short Kl[32 * 64];  // [kv][d], chunk-swizzled
  __shared__ __align__(16) unsigned short Vl[64 * 32];  // [d][t], chunk-swizzled
  __shared__ __align__(16) unsigned short Pl[4][16 * 32];

  const int tid = threadIdx.x;
  const int w = tid >> 6, lane = tid & 63;
  const int g = lane >> 4, c16 = lane & 15;
  const int bh = blockIdx.y;
  const int bb = bh / H_, hh = bh % H_;
  const int qb0 = blockIdx.x * 64;
  const int q0 = qb0 + w * 16;

  const size_t hoff = (size_t)bh * T_ * D_;
  const unsigned short* Qh = Qb + hoff;
  const unsigned short* Kh = Kb + hoff;
  const unsigned short* Vh = Vt + hoff;  // [64][4096]

  const bf16x8 qf0 = *reinterpret_cast<const bf16x8*>(&Qh[(size_t)(q0 + c16) * D_ + g * 8]);
  const bf16x8 qf1 = *reinterpret_cast<const bf16x8*>(&Qh[(size_t)(q0 + c16) * D_ + 32 + g * 8]);

  float mrun = -__builtin_inff(), lrun = 0.f;
  f32x4 y[4] = {};

  const int nkv = (qb0 + 95) >> 5;  // ceil((qb0+64)/32)

  // staging: one 16B K-chunk + one 16B V-chunk per thread; source pre-swizzled
  const int krow = tid >> 3;                       // 0..31 (kv row)
  const int kch  = (tid & 7) ^ (krow & 7);         // global d-chunk for linear LDS slot
  const int vrow = tid >> 2;                       // 0..63 (d row)
  const int vch  = (tid & 3) ^ (vrow & 3);         // global t-chunk

  char* PlW = (char*)&Pl[w][0];
  const int prow = c16 * 64;
  const int pxor = (c16 & 3) << 4;

  for (int i = 0; i < nkv; ++i) {
    const int kv0 = i * 32;
    __syncthreads();
    gload_lds16(Kh + (size_t)(kv0 + krow) * D_ + kch * 8, &Kl[w * 512]);
    gload_lds16(Vh + (size_t)vrow * T_ + kv0 + vch * 8,   &Vl[w * 512]);
    __syncthreads();

    // S^T tiles: mfma(K, Q) -> lane holds q = c16, kv = g*4+j (+16 for tile1)
    const int r0 = c16, r1 = 16 + c16;
    const bf16x8 kf00 = *reinterpret_cast<const bf16x8*>(&Kl[r0 * 64 + ((g     ^ (r0 & 7)) * 8)]);
    const bf16x8 kf01 = *reinterpret_cast<const bf16x8*>(&Kl[r0 * 64 + (((g+4) ^ (r0 & 7)) * 8)]);
    const bf16x8 kf10 = *reinterpret_cast<const bf16x8*>(&Kl[r1 * 64 + ((g     ^ (r1 & 7)) * 8)]);
    const bf16x8 kf11 = *reinterpret_cast<const bf16x8*>(&Kl[r1 * 64 + (((g+4) ^ (r1 & 7)) * 8)]);

    const f32x4 z = {0.f, 0.f, 0.f, 0.f};
    f32x4 st0 = __builtin_amdgcn_mfma_f32_16x16x32_bf16(kf00, qf0, z, 0, 0, 0);
    st0 = __builtin_amdgcn_mfma_f32_16x16x32_bf16(kf01, qf1, st0, 0, 0, 0);
    f32x4 st1 = __builtin_amdgcn_mfma_f32_16x16x32_bf16(kf10, qf0, z, 0, 0, 0);
    st1 = __builtin_amdgcn_mfma_f32_16x16x32_bf16(kf11, qf1, st1, 0, 0, 0);

    if (kv0 + 31 > q0) {  // wave-uniform: diagonal or beyond-extent tile
      const int qg = q0 + c16;
      #pragma unroll
      for (int j = 0; j < 4; ++j) {
        st0[j] = (kv0 + g * 4 + j > qg)      ? -__builtin_inff() : st0[j];
        st1[j] = (kv0 + 16 + g * 4 + j > qg) ? -__builtin_inff() : st1[j];
      }
    }

    float tmax = fmaxf(fmaxf(fmaxf(st0[0], st0[1]), fmaxf(st0[2], st0[3])),
                       fmaxf(fmaxf(st1[0], st1[1]), fmaxf(st1[2], st1[3])));
    tmax = fmaxf(tmax, __shfl_xor(tmax, 16));
    tmax = fmaxf(tmax, __shfl_xor(tmax, 32));
    const float mnew = fmaxf(mrun, tmax);
    const float alpha = __expf(mrun - mnew);
    float p[8];
    #pragma unroll
    for (int j = 0; j < 4; ++j) {
      p[j]     = __expf(st0[j] - mnew);
      p[4 + j] = __expf(st1[j] - mnew);
    }
    float rsum = (p[0] + p[1]) + (p[2] + p[3]) + (p[4] + p[5]) + (p[6] + p[7]);
    rsum += __shfl_xor(rsum, 16);
    rsum += __shfl_xor(rsum, 32);
    lrun = lrun * alpha + rsum;
    mrun = mnew;

    #pragma unroll
    for (int j = 0; j < 4; ++j) {
      const float aj = __shfl(alpha, g * 4 + j);  // alpha of q-row g*4+j
      y[0][j] *= aj; y[1][j] *= aj; y[2][j] *= aj; y[3][j] *= aj;
    }

    // P -> per-wave LDS (swizzled) -> A-fragment for PV
    #pragma unroll
    for (int t2 = 0; t2 < 2; ++t2) {
      #pragma unroll
      for (int pr = 0; pr < 2; ++pr) {
        const int kv = t2 * 16 + g * 4 + pr * 2;
        *(uint32_t*)(PlW + prow + ((kv * 2) ^ pxor)) =
            pk2bf(p[t2 * 4 + pr * 2], p[t2 * 4 + pr * 2 + 1]);
      }
    }
    const bf16x8 pf = *(const bf16x8*)(PlW + prow + ((g * 16) ^ pxor));

    #pragma unroll
    for (int db = 0; db < 4; ++db) {
      const int d = db * 16 + c16;
      const bf16x8 vf = *(const bf16x8*)((char*)&Vl[0] + d * 64 + ((g * 16) ^ ((d & 3) << 4)));
      y[db] = __builtin_amdgcn_mfma_f32_16x16x32_bf16(pf, vf, y[db], 0, 0, 0);
    }
  }

  // epilogue: normalize by l and store to Y[B][T][C] (bf16)
  #pragma unroll
  for (int j = 0; j < 4; ++j) {
    const float lj = __shfl(lrun, g * 4 + j);
    const float inv = 1.f / lj;
    const int qg = q0 + g * 4 + j;
    const size_t ro = ((size_t)bb * T_ + qg) * C_ + hh * D_;
    #pragma unroll
    for (int db = 0; db < 4; ++db)
      Yb[ro + db * 16 + c16] = f2bf(y[db][j] * inv);
  }
}

// ---------------------------------------------------------------- launch
extern "C" void kernel_launch(void* const* d_in, const int* in_sizes, int n_in,
                              void* d_out, int out_size, void* d_ws, size_t ws_size,
                              hipStream_t stream) {
  const float* x      = (const float*)d_in[0];
  const float* w_attn = (const float*)d_in[1];
  const float* b_attn = (const float*)d_in[2];
  const float* w_proj = (const float*)d_in[3];
  const float* b_proj = (const float*)d_in[4];
  float* out = (float*)d_out;

  char* ws = (char*)d_ws;
  size_t off = 0;
  auto alloc = [&](size_t bytes) -> void* {
    void* p = ws + off;
    off += (bytes + 255) & ~(size_t)255;
    return p;
  };
  unsigned short* xb  = (unsigned short*)alloc((size_t)M_ * K_ * 2);       // x bf16
  unsigned short* waT = (unsigned short*)alloc((size_t)N1_ * K_ * 2);      // w_attn^T bf16
  unsigned short* wpT = (unsigned short*)alloc((size_t)C_ * K_ * 2);       // w_proj^T bf16
  unsigned short* Qb  = (unsigned short*)alloc((size_t)BH_ * T_ * D_ * 2); // [BH][T][D]
  unsigned short* Kb  = (unsigned short*)alloc((size_t)BH_ * T_ * D_ * 2);
  unsigned short* Vt  = (unsigned short*)alloc((size_t)BH_ * D_ * T_ * 2); // [BH][D][T]
  unsigned short* Yb  = (unsigned short*)alloc((size_t)M_ * C_ * 2);       // attn out bf16

  cast_kernel<<<1024, 256, 0, stream>>>(x, xb, M_ * K_ / 4);
  transpose_cast<<<dim3(N1_ / 32, K_ / 32), dim3(32, 8), 0, stream>>>(w_attn, waT, K_, N1_);
  transpose_cast<<<dim3(C_ / 32, K_ / 32), dim3(32, 8), 0, stream>>>(w_proj, wpT, K_, C_);

  gemm_kernel<0><<<dim3(M_ / 128, N1_ / 128), 256, 0, stream>>>(
      xb, waT, b_attn, Qb, Kb, Vt, nullptr);

  attn_kernel<<<dim3(T_ / 64, BH_), 256, 0, stream>>>(Qb, Kb, Vt, Yb);

  gemm_kernel<1><<<dim3(M_ / 128, C_ / 128), 256, 0, stream>>>(
      Yb, wpT, b_proj, nullptr, nullptr, nullptr, out);
}